// Round 1
// 467.074 us; speedup vs baseline: 1.1478x; 1.1478x over previous
//
#include <hip/hip_runtime.h>

#define K_TAGS 50
#define T_MAX 256
#define START_TAG 48
#define END_TAG 49
#define LOG2E 1.4426950408889634f
#define LN2 0.6931471805599453f
#define KK 2500   // dwords per 50x50 step matrix

// hardware transcendentals: v_exp_f32 is 2^x, v_log_f32 is log2(x)
#define EXP2F(x) __builtin_amdgcn_exp2f(x)
#define LOG2F(x) __builtin_amdgcn_logf(x)

__device__ __forceinline__ float rdlane(float v, int i) {
    return __int_as_float(__builtin_amdgcn_readlane(__float_as_int(v), i));
}

// TWO WAVES PER BATCH ELEMENT, meeting in the middle.
//   Z_b = alpha0^T * G_1 * G_2 * ... * G_{len-1} * e_END   (G_t = exp(s_t))
// wave 0: forward  u^T <- u^T G_t   for t = 1..m          (column-owned, as before)
// wave 1: backward v   <- G_t v     for t = len-1..m+1    (row contraction)
//   Z_b = sum_j u_m[j] * v_m[j]
// Both are scaled-linear recursions (exponent M + normalized linear L), identical
// numerics to the previous single-chain kernel. The backward wave keeps the
// coalesced column loads and transposes the EXP'd matrix through LDS at prefetch
// time (exp leaves the critical path); row reads are 25x ds_read_b64 per step.
// Split is biased 9:7 toward forward to cover backward's LDS round-trip.
__global__ __launch_bounds__(128, 1) void crf_fwd_kernel(
    const float* __restrict__ scores, const int* __restrict__ targets,
    const int* __restrict__ lengths, float* __restrict__ accum)
{
    const int b   = blockIdx.x;
    const int tid = threadIdx.x;
    const int len = lengths[b];
    const float* __restrict__ sp = scores + (size_t)b * T_MAX * KK;

    __shared__ __align__(16) float tbuf[2][KK];  // backward: exp'd transposed step matrices
    __shared__ float cVb[64];                    // backward result vector v_m
    __shared__ float cMb;                        // backward exponent

    // forward steps: t = 1..m ; backward steps: t = len-1..m+1
    const int m = ((len - 1) * 9) >> 4;

    // ---- gold score (fused): 2 timesteps per thread, per-wave reduce, 2 atomics ----
    {
        float g = 0.f;
        #pragma unroll
        for (int q = 0; q < 2; ++q) {
            int t = tid + 128 * q;
            if (t < len) {
                int tg = targets[b * T_MAX + t];
                g += sp[(size_t)t * KK + tg];
            }
        }
        #pragma unroll
        for (int off = 32; off; off >>= 1) g += __shfl_down(g, off, 64);
        if ((tid & 63) == 0) atomicAdd(&accum[1], g);
    }

    float fM = 0.f, fL = 0.f;   // forward result (wave 0 only)

    if (tid < 64) {
        // ======================= wave 0: forward half =======================
        const int lane = tid;
        const int j = (lane < K_TAGS) ? lane : (K_TAGS - 1);

        float bcur = sp[START_TAG * K_TAGS + j] * LOG2E;
        float M = rdlane(bcur, 0);
        float L = EXP2F(bcur - M);

        float S0[50], S1[50], P0[50], P1[50];

        auto loadcol = [&](float (&dst)[50], int t) {
            int tc = (t < len) ? t : (len - 1);
            const float* s = sp + (size_t)tc * KK + j;
            #pragma unroll
            for (int i = 0; i < 50; ++i) dst[i] = s[i * K_TAGS];
        };

        auto step_fn = [&](const float (&Pc)[50]) {
            float l0 = rdlane(L, 0);
            int   ei = (__float_as_int(l0) >> 23) & 0xFF;        // biased exponent
            float scale = __int_as_float((254 - ei) << 23);      // 2^-(ei-127)
            float a0 = 0.f, a1 = 0.f, a2 = 0.f, a3 = 0.f, a4 = 0.f;
            #pragma unroll
            for (int i = 0; i < 50; i += 5) {
                a0 = __builtin_fmaf(Pc[i + 0], rdlane(L, i + 0), a0);
                a1 = __builtin_fmaf(Pc[i + 1], rdlane(L, i + 1), a1);
                a2 = __builtin_fmaf(Pc[i + 2], rdlane(L, i + 2), a2);
                a3 = __builtin_fmaf(Pc[i + 3], rdlane(L, i + 3), a3);
                a4 = __builtin_fmaf(Pc[i + 4], rdlane(L, i + 4), a4);
            }
            L = (((a0 + a1) + (a2 + a3)) + a4) * scale;
            M += (float)(ei - 127);
        };

        const int fend = m + 1;   // exclusive upper bound on forward t
        loadcol(S1, 1);
        loadcol(S0, 2);
        __builtin_amdgcn_sched_barrier(0);
        #pragma unroll
        for (int i = 0; i < 50; ++i) P1[i] = EXP2F(S1[i] * LOG2E);

        int t = 1;
        while (t < fend) {
            loadcol(S1, t + 2);
            __builtin_amdgcn_sched_barrier(0);
            #pragma unroll
            for (int i = 0; i < 50; ++i) P0[i] = EXP2F(S0[i] * LOG2E);
            step_fn(P1);
            if (++t >= fend) break;

            loadcol(S0, t + 2);
            __builtin_amdgcn_sched_barrier(0);
            #pragma unroll
            for (int i = 0; i < 50; ++i) P1[i] = EXP2F(S1[i] * LOG2E);
            step_fn(P0);
            ++t;
        }
        fM = M; fL = L;
    } else {
        // ======================= wave 1: backward half =======================
        const int wl = tid - 64;
        const int p  = (wl < K_TAGS) ? wl : (K_TAGS - 1);   // owned row index

        float Mv = 0.f, Lv = (p == END_TAG) ? 1.f : 0.f;
        const int tstop = m + 1;
        int t = len - 1;

        if (t >= tstop) {
            // first step folded: v[p] = exp(s_t[p][END]) * 1
            float s0 = sp[(size_t)t * KK + p * K_TAGS + END_TAG];
            Lv = EXP2F(s0 * LOG2E);
            --t;
        }
        if (t >= tstop) {
            float CA[50], CB[50], R[50];

            auto loadcolB = [&](float (&dst)[50], int tt) {
                int tc = (tt >= tstop) ? tt : tstop;   // clamp; surplus loads unused
                const float* s = sp + (size_t)tc * KK + p;
                #pragma unroll
                for (int i = 0; i < 50; ++i) dst[i] = s[i * K_TAGS];
            };
            // exp the staged columns and write TRANSPOSED into LDS (off critical path)
            auto expwrite = [&](float* tb, const float (&C)[50]) {
                #pragma unroll
                for (int i = 0; i < 50; ++i) tb[i * K_TAGS + p] = EXP2F(C[i] * LOG2E);
            };
            auto stepB = [&](const float* tb) {
                const float2* r2 = reinterpret_cast<const float2*>(tb + p * K_TAGS);
                #pragma unroll
                for (int k = 0; k < 25; ++k)
                    *reinterpret_cast<float2*>(&R[2 * k]) = r2[k];
                float l0 = rdlane(Lv, 0);
                int   ei = (__float_as_int(l0) >> 23) & 0xFF;
                float scale = __int_as_float((254 - ei) << 23);
                float a0 = 0.f, a1 = 0.f, a2 = 0.f, a3 = 0.f, a4 = 0.f;
                #pragma unroll
                for (int i = 0; i < 50; i += 5) {
                    a0 = __builtin_fmaf(R[i + 0], rdlane(Lv, i + 0), a0);
                    a1 = __builtin_fmaf(R[i + 1], rdlane(Lv, i + 1), a1);
                    a2 = __builtin_fmaf(R[i + 2], rdlane(Lv, i + 2), a2);
                    a3 = __builtin_fmaf(R[i + 3], rdlane(Lv, i + 3), a3);
                    a4 = __builtin_fmaf(R[i + 4], rdlane(Lv, i + 4), a4);
                }
                Lv = (((a0 + a1) + (a2 + a3)) + a4) * scale;
                Mv += (float)(ei - 127);
            };

            // prologue: tbuf0 = P(t)^T, CB = s(t-1)
            loadcolB(CA, t);
            __builtin_amdgcn_sched_barrier(0);
            expwrite(tbuf[0], CA);
            loadcolB(CB, t - 1);
            __builtin_amdgcn_sched_barrier(0);

            while (t >= tstop) {
                // step t from tbuf0; stage P(t-1) into tbuf1; prefetch s(t-2)
                loadcolB(CA, t - 2);
                __builtin_amdgcn_sched_barrier(0);
                expwrite(tbuf[1], CB);
                stepB(tbuf[0]);
                if (--t < tstop) break;

                loadcolB(CB, t - 2);
                __builtin_amdgcn_sched_barrier(0);
                expwrite(tbuf[0], CA);
                stepB(tbuf[1]);
                --t;
            }
        }
        cVb[wl] = Lv;
        if (wl == 0) cMb = Mv;
    }

    __syncthreads();

    if (tid < 64) {
        // ---- combine: Z = fM + Mb + log2( sum_j fL[j] * v[j] ) ----
        float prod = (tid < K_TAGS) ? fL * cVb[tid] : 0.f;
        #pragma unroll
        for (int off = 32; off; off >>= 1) prod += __shfl_down(prod, off, 64);
        if (tid == 0) {
            float z = (fM + cMb + LOG2F(prod)) * LN2;   // back to natural log
            atomicAdd(&accum[0], z);
        }
    }
}

__global__ void finalize_kernel(const float* __restrict__ accum,
                                float* __restrict__ out, float invB)
{
    out[0] = (accum[0] - accum[1]) * invB;
}

extern "C" void kernel_launch(void* const* d_in, const int* in_sizes, int n_in,
                              void* d_out, int out_size, void* d_ws, size_t ws_size,
                              hipStream_t stream)
{
    const float* scores  = (const float*)d_in[0];
    const int*   targets = (const int*)d_in[1];
    const int*   lengths = (const int*)d_in[2];
    const int B = in_sizes[2];

    float* accum = (float*)d_ws;
    hipMemsetAsync(accum, 0, 2 * sizeof(float), stream);
    crf_fwd_kernel<<<B, 128, 0, stream>>>(scores, targets, lengths, accum);
    finalize_kernel<<<1, 1, 0, stream>>>(accum, (float*)d_out, 1.0f / (float)B);
}